// Round 2
// baseline (154.565 us; speedup 1.0000x reference)
//
#include <hip/hip_runtime.h>

// Duration-based length regulation. B=8, T=512, D=512, MAX_LEN = T*15 = 7680.
// features fp32 (B,T,D), durations int32 (B,T), out fp32 (B,MAX_LEN,D).
//
// Two-phase structure (R7/R8): phase 1 computes the frame->phoneme index map
// once per batch via scan+scatter (no binary searches); phase 2 is a pure
// gather-copy that should run at store bandwidth. Prior single-kernel best
// (145.1 us) was latency-bound on 2048 redundant scans + 10-deep dependent
// LDS binary-search chains per frame.
// R8 fix: __builtin_nontemporal_store needs a native clang vector type,
// not HIP_vector_type<float,4> — reinterpret through ext_vector_type.
#define BB 8
#define TT 512
#define DD 512
#define MAX_LEN 7680
#define FPB 30                        // frames per block (phase 2)
#define BPB (MAX_LEN / FPB)           // 256 blocks per batch

typedef float f32x4 __attribute__((ext_vector_type(4)));

// ---------------- Phase 1: one block per batch ----------------
// Scan clamped durations, scatter idx map into workspace. idx = -1 marks
// padding frames (n >= total); scatter covers exactly [0, total).
__global__ __launch_bounds__(256) void build_idx_kernel(
    const int2* __restrict__ dur2,     // (B, T/2)
    int*        __restrict__ idx_ws)   // (B, MAX_LEN)
{
    __shared__ int ps[256];            // pair partial sums for the scan
    __shared__ int idx_s[MAX_LEN];     // 30 KB

    const int t = threadIdx.x;
    const int b = blockIdx.x;

    int2 dd = dur2[b * (TT / 2) + t];
    int d0 = dd.x < 1 ? 1 : dd.x;
    int d1 = dd.y < 1 ? 1 : dd.y;
    ps[t] = d0 + d1;

    // init padding marker
    for (int j = t; j < MAX_LEN; j += 256) idx_s[j] = -1;
    __syncthreads();

    // Hillis-Steele inclusive scan over 256 pair-sums (verified pattern)
#pragma unroll
    for (int off = 1; off < 256; off <<= 1) {
        int x = (t >= off) ? ps[t - off] : 0;
        __syncthreads();
        ps[t] += x;
        __syncthreads();
    }
    const int incl = ps[t];            // cum[2t+1] inclusive
    const int s1   = incl - d1;        // start of phoneme 2t+1 (= end of 2t)
    const int s0   = s1 - d0;          // start of phoneme 2t

    // scatter: each phoneme writes its own output-frame range (1..15 entries)
    for (int k = s0; k < s1; ++k)   idx_s[k] = 2 * t;
    for (int k = s1; k < incl; ++k) idx_s[k] = 2 * t + 1;
    __syncthreads();

    // coalesced dump to workspace
    for (int j = t; j < MAX_LEN; j += 256)
        idx_ws[b * MAX_LEN + j] = idx_s[j];
}

// ---------------- Phase 2: streaming gather-copy ----------------
__global__ __launch_bounds__(256) void expand_kernel(
    const float4* __restrict__ feat,   // (B, T, DD/4)
    const int*    __restrict__ idx_ws, // (B, MAX_LEN)
    float4*       __restrict__ out)    // (B, MAX_LEN, DD/4)
{
    __shared__ int idx_s[FPB];

    const int t    = threadIdx.x;
    const int b    = blockIdx.x / BPB;
    const int base = (blockIdx.x % BPB) * FPB;

    if (t < FPB) idx_s[t] = idx_ws[b * MAX_LEN + base + t];
    __syncthreads();

    const int lane = t & 127;          // 128 lanes x float4 = one 2 KB row
    const int sub  = t >> 7;           // two frames in flight per iteration

#pragma unroll
    for (int j = 0; j < FPB; j += 2) {
        const int n   = base + j + sub;
        const int src = idx_s[j + sub];            // LDS broadcast
        float4 val = make_float4(0.f, 0.f, 0.f, 0.f);
        if (src >= 0)
            val = feat[(size_t)(b * TT + src) * (DD / 4) + lane];
        // output is never re-read: keep it out of L2 so feat stays resident
        __builtin_nontemporal_store(
            *(const f32x4*)&val,
            (f32x4*)&out[((size_t)b * MAX_LEN + n) * (DD / 4) + lane]);
    }
}

// ---------------- Fallback: prior verified single-kernel path ----------------
__global__ __launch_bounds__(256) void regulate_kernel(
    const float4* __restrict__ feat,
    const int2*   __restrict__ dur2,
    float4*       __restrict__ out)
{
    __shared__ int cum[TT];
    __shared__ int ps[256];

    const int t    = threadIdx.x;
    const int b    = blockIdx.x / BPB;
    const int base = (blockIdx.x % BPB) * FPB;

    int2 dd = dur2[b * (TT / 2) + t];
    int d0 = dd.x < 1 ? 1 : dd.x;
    int d1 = dd.y < 1 ? 1 : dd.y;
    ps[t] = d0 + d1;
    __syncthreads();
#pragma unroll
    for (int off = 1; off < 256; off <<= 1) {
        int x = (t >= off) ? ps[t - off] : 0;
        __syncthreads();
        ps[t] += x;
        __syncthreads();
    }
    int incl = ps[t];
    cum[2 * t]     = incl - d1;
    cum[2 * t + 1] = incl;
    __syncthreads();

    const int total = cum[TT - 1];
    const int lane  = t & 127;
    const int sub   = t >> 7;

#pragma unroll
    for (int j = 0; j < FPB; j += 2) {
        const int n = base + j + sub;
        float4 val = make_float4(0.f, 0.f, 0.f, 0.f);
        if (n < total) {
            int lo = 0, hi = TT;
#pragma unroll
            for (int s = 0; s < 10; ++s) {
                int mid = (lo + hi) >> 1;
                if (cum[mid] <= n) lo = mid + 1; else hi = mid;
            }
            val = feat[(size_t)(b * TT + lo) * (DD / 4) + lane];
        }
        out[((size_t)b * MAX_LEN + n) * (DD / 4) + lane] = val;
    }
}

extern "C" void kernel_launch(void* const* d_in, const int* in_sizes, int n_in,
                              void* d_out, int out_size, void* d_ws, size_t ws_size,
                              hipStream_t stream) {
    const float* feat;
    const int*   dur;
    if (in_sizes[0] == BB * TT) {
        dur  = (const int*)d_in[0];
        feat = (const float*)d_in[1];
    } else {
        feat = (const float*)d_in[0];
        dur  = (const int*)d_in[1];
    }
    float* out = (float*)d_out;

    const size_t idx_bytes = (size_t)BB * MAX_LEN * sizeof(int);
    if (d_ws != nullptr && ws_size >= idx_bytes) {
        int* idx_ws = (int*)d_ws;
        build_idx_kernel<<<BB, 256, 0, stream>>>((const int2*)dur, idx_ws);
        expand_kernel<<<BB * BPB, 256, 0, stream>>>(
            (const float4*)feat, idx_ws, (float4*)out);
    } else {
        // workspace too small: verified single-kernel fallback
        regulate_kernel<<<BB * BPB, 256, 0, stream>>>(
            (const float4*)feat, (const int2*)dur, (float4*)out);
    }
}

// Round 3
// 151.575 us; speedup vs baseline: 1.0197x; 1.0197x over previous
//
#include <hip/hip_runtime.h>

// Duration-based length regulation. B=8, T=512, D=512, MAX_LEN = T*15 = 7680.
// features fp32 (B,T,D), durations int32 (B,T), out fp32 (B,MAX_LEN,D).
//
// R9: single kernel, NO workspace (R8's two-phase was correct but the
// harness re-poisons the 480 MiB workspace per iteration -> ~80 us fill
// visible in counters, eating the win). Replaces the baseline's 10-deep
// dependent binary-search chains with a bounded scatter: after the pair
// scan each thread writes its two phonemes' indices into the block-local
// frame window [base, base+FPB) directly. No searches, no cum[] array.
#define BB 8
#define TT 512
#define DD 512
#define MAX_LEN 7680
#define FPB 30                        // frames per block
#define BPB (MAX_LEN / FPB)           // 256 blocks per batch

typedef float f32x4 __attribute__((ext_vector_type(4)));

__global__ __launch_bounds__(256) void regulate_kernel(
    const float4* __restrict__ feat,   // (B, T, DD/4)
    const int2*   __restrict__ dur2,   // (B, T/2)
    float4*       __restrict__ out)    // (B, MAX_LEN, DD/4)
{
    __shared__ int ps[256];            // pair partial sums for the scan
    __shared__ int idx_s[FPB];         // frame -> phoneme for this window

    const int t    = threadIdx.x;
    const int b    = blockIdx.x / BPB;
    const int base = (blockIdx.x % BPB) * FPB;

    // ---- load 2 durations/thread, clamp(min=1) ----
    int2 dd = dur2[b * (TT / 2) + t];
    int d0 = dd.x < 1 ? 1 : dd.x;
    int d1 = dd.y < 1 ? 1 : dd.y;
    ps[t] = d0 + d1;

    // padding marker for frames beyond the batch's total length
    if (t < FPB) idx_s[t] = -1;
    __syncthreads();

    // ---- Hillis-Steele inclusive scan over 256 pair-sums (verified) ----
#pragma unroll
    for (int off = 1; off < 256; off <<= 1) {
        int x = (t >= off) ? ps[t - off] : 0;
        __syncthreads();
        ps[t] += x;
        __syncthreads();
    }
    const int incl = ps[t];            // cum[2t+1] inclusive
    const int s1   = incl - d1;        // start of phoneme 2t+1 (= end of 2t)
    const int s0   = s1 - d0;          // start of phoneme 2t

    // ---- bounded scatter into this block's window [base, base+FPB) ----
    // (scan barriers above guarantee the idx_s init is visible)
    const int lim = base + FPB;
    {
        int k0 = s0 > base ? s0 : base;
        int k1 = s1 < lim  ? s1 : lim;
        for (int k = k0; k < k1; ++k) idx_s[k - base] = 2 * t;
        int k2 = s1 > base ? s1 : base;
        int k3 = incl < lim ? incl : lim;
        for (int k = k2; k < k3; ++k) idx_s[k - base] = 2 * t + 1;
    }
    __syncthreads();

    // ---- streaming gather-copy: 2 frames in flight per iteration ----
    const int lane = t & 127;          // 128 lanes x float4 = one 2 KB row
    const int sub  = t >> 7;

#pragma unroll
    for (int j = 0; j < FPB; j += 2) {
        const int n   = base + j + sub;
        const int src = idx_s[j + sub];            // LDS broadcast
        float4 val = make_float4(0.f, 0.f, 0.f, 0.f);
        if (src >= 0)
            val = feat[(size_t)(b * TT + src) * (DD / 4) + lane];
        // output is never re-read: keep it out of L2 so feat stays resident
        __builtin_nontemporal_store(
            *(const f32x4*)&val,
            (f32x4*)&out[((size_t)b * MAX_LEN + n) * (DD / 4) + lane]);
    }
}

extern "C" void kernel_launch(void* const* d_in, const int* in_sizes, int n_in,
                              void* d_out, int out_size, void* d_ws, size_t ws_size,
                              hipStream_t stream) {
    // Select pointers by element count (features = B*T*D = 2097152, dur = 4096)
    const float* feat;
    const int*   dur;
    if (in_sizes[0] == BB * TT) {
        dur  = (const int*)d_in[0];
        feat = (const float*)d_in[1];
    } else {
        feat = (const float*)d_in[0];
        dur  = (const int*)d_in[1];
    }
    float* out = (float*)d_out;        // (B, MAX_LEN, D) fp32

    regulate_kernel<<<BB * BPB, 256, 0, stream>>>(
        (const float4*)feat, (const int2*)dur, (float4*)out);
}

// Round 4
// 138.874 us; speedup vs baseline: 1.1130x; 1.0915x over previous
//
#include <hip/hip_runtime.h>

// Duration-based length regulation. B=8, T=512, D=512, MAX_LEN = T*15 = 7680.
// features fp32 (B,T,D), durations int32 (B,T), out fp32 (B,MAX_LEN,D).
//
// R10: run-detection gather-copy. R3 showed the binary-search removal was
// neutral (searches were TLP-hidden) and that ~80us of measured time is the
// harness's unconditional workspace poison fill. The copy itself runs at
// ~1.8 TB/s because every store waits on its own gather load. Mean clamped
// duration is ~7.6, so the source row changes rarely: detect runs, load each
// distinct row once into registers, and give each thread a CONTIGUOUS frame
// range (sub*15..sub*15+14) so runs are not split across thread groups.
// NT stores dropped (R3: slightly worse than plain; fill hits 6.3 TB/s plain).
#define BB 8
#define TT 512
#define DD 512
#define MAX_LEN 7680
#define FPB 30                        // frames per block
#define HPB (FPB / 2)                 // frames per thread-subgroup (15)
#define BPB (MAX_LEN / FPB)           // 256 blocks per batch

__global__ __launch_bounds__(256) void regulate_kernel(
    const float4* __restrict__ feat,   // (B, T, DD/4)
    const int2*   __restrict__ dur2,   // (B, T/2)
    float4*       __restrict__ out)    // (B, MAX_LEN, DD/4)
{
    __shared__ int ps[256];            // pair partial sums for the scan
    __shared__ int idx_s[FPB];         // frame -> phoneme for this window

    const int t    = threadIdx.x;
    const int b    = blockIdx.x / BPB;
    const int base = (blockIdx.x % BPB) * FPB;

    // ---- load 2 durations/thread, clamp(min=1) ----
    int2 dd = dur2[b * (TT / 2) + t];
    int d0 = dd.x < 1 ? 1 : dd.x;
    int d1 = dd.y < 1 ? 1 : dd.y;
    ps[t] = d0 + d1;

    // padding marker for frames beyond the batch's total length
    if (t < FPB) idx_s[t] = -1;
    __syncthreads();

    // ---- Hillis-Steele inclusive scan over 256 pair-sums (verified) ----
#pragma unroll
    for (int off = 1; off < 256; off <<= 1) {
        int x = (t >= off) ? ps[t - off] : 0;
        __syncthreads();
        ps[t] += x;
        __syncthreads();
    }
    const int incl = ps[t];            // cum[2t+1] inclusive
    const int s1   = incl - d1;        // start of phoneme 2t+1 (= end of 2t)
    const int s0   = s1 - d0;          // start of phoneme 2t

    // ---- bounded scatter into this block's window [base, base+FPB) ----
    // (verified in R3: absmax 0.0)
    const int lim = base + FPB;
    {
        int k0 = s0 > base ? s0 : base;
        int k1 = s1 < lim  ? s1 : lim;
        for (int k = k0; k < k1; ++k) idx_s[k - base] = 2 * t;
        int k2 = s1 > base ? s1 : base;
        int k3 = incl < lim ? incl : lim;
        for (int k = k2; k < k3; ++k) idx_s[k - base] = 2 * t + 1;
    }
    __syncthreads();

    // ---- run-detection streaming copy ----
    // lane = float4 column within the 2 KB row; sub picks a contiguous
    // 15-frame range so a duration-run stays within one thread.
    const int lane = t & 127;
    const int sub  = t >> 7;
    const float4* featb = feat + (size_t)b * TT * (DD / 4) + lane;
    float4*       outb  = out  + ((size_t)b * MAX_LEN + base + sub * HPB) * (DD / 4) + lane;

    int    prev = -2;                  // forces a load on first iteration
    float4 val  = make_float4(0.f, 0.f, 0.f, 0.f);
#pragma unroll
    for (int j = 0; j < HPB; ++j) {
        const int src = idx_s[sub * HPB + j];      // LDS broadcast, wave-uniform
        if (src != prev) {                         // wave-uniform branch
            val = (src >= 0) ? featb[(size_t)src * (DD / 4)]
                             : make_float4(0.f, 0.f, 0.f, 0.f);
            prev = src;
        }
        outb[(size_t)j * (DD / 4)] = val;
    }
}

extern "C" void kernel_launch(void* const* d_in, const int* in_sizes, int n_in,
                              void* d_out, int out_size, void* d_ws, size_t ws_size,
                              hipStream_t stream) {
    // Select pointers by element count (features = B*T*D = 2097152, dur = 4096)
    const float* feat;
    const int*   dur;
    if (in_sizes[0] == BB * TT) {
        dur  = (const int*)d_in[0];
        feat = (const float*)d_in[1];
    } else {
        feat = (const float*)d_in[0];
        dur  = (const int*)d_in[1];
    }
    float* out = (float*)d_out;        // (B, MAX_LEN, D) fp32

    regulate_kernel<<<BB * BPB, 256, 0, stream>>>(
        (const float4*)feat, (const int2*)dur, (float4*)out);
}